// Round 19
// baseline (138.023 us; speedup 1.0000x reference)
//
#include <hip/hip_runtime.h>
#include <stdint.h>
#include <stddef.h>

// ---------- types ----------
typedef __attribute__((ext_vector_type(8))) short s16x8;
typedef __attribute__((ext_vector_type(4))) short s16x4;
typedef __attribute__((ext_vector_type(4))) float f32x4;
typedef __attribute__((ext_vector_type(2))) unsigned int u32x2;

#define MFMA(a,b,c) __builtin_amdgcn_mfma_f32_16x16x32_bf16((a),(b),(c),0,0,0)

static __device__ __forceinline__ unsigned short f2b(float f){
  unsigned int b = __float_as_uint(f);
  b = (b + 0x7FFFu + ((b>>16)&1u)) >> 16;     // RNE
  return (unsigned short)b;
}
static __device__ __forceinline__ float b2f(unsigned short u){
  return __uint_as_float(((unsigned int)u)<<16);
}

// B=2, T1=1024, T2=512, H=16, DH=64, DM=1024, SCALE=0.125

// ---------- fused prep: LN(Q), gather K/V, cast L, transpose weights, mask pack ----------
__global__ __launch_bounds__(256) void k_prep(
    const float* __restrict__ Q, const float* __restrict__ g, const float* __restrict__ be,
    unsigned short* __restrict__ Qn,
    const float* __restrict__ K, const float* __restrict__ V, const int* __restrict__ vf,
    unsigned short* __restrict__ Kg, unsigned short* __restrict__ Vg,
    const float* __restrict__ L, unsigned short* __restrict__ Lb,
    const float* __restrict__ W0, const float* __restrict__ W1,
    const float* __restrict__ W2, const float* __restrict__ W3,
    unsigned short* __restrict__ D0, unsigned short* __restrict__ D1,
    unsigned short* __restrict__ D2, unsigned short* __restrict__ D3,
    const unsigned char* __restrict__ mkb, unsigned int* __restrict__ MB){
  __shared__ float tile[64][65];
  __shared__ float red[8];
  __shared__ int cnt1, cnt23;
  const int bid = blockIdx.x, t = threadIdx.x;
  if(bid < 2048){                       // ---- LayerNorm ----
    const float4* xp = (const float4*)(Q + (size_t)bid*1024);
    float4 v = xp[t];
    float s  = v.x+v.y+v.z+v.w;
    float s2 = v.x*v.x+v.y*v.y+v.z*v.z+v.w*v.w;
    #pragma unroll
    for(int o=1;o<64;o<<=1){ s += __shfl_xor(s,o); s2 += __shfl_xor(s2,o); }
    int w = t>>6, l = t&63;
    if(l==0){ red[w]=s; red[4+w]=s2; }
    __syncthreads();
    s  = red[0]+red[1]+red[2]+red[3];
    s2 = red[4]+red[5]+red[6]+red[7];
    float mu = s*(1.f/1024.f);
    float var = s2*(1.f/1024.f) - mu*mu;
    float rs = rsqrtf(var + 1e-5f);
    float4 gv = ((const float4*)g)[t];
    float4 bv = ((const float4*)be)[t];
    ushort4 o4;
    o4.x = f2b((v.x-mu)*rs*gv.x + bv.x);
    o4.y = f2b((v.y-mu)*rs*gv.y + bv.y);
    o4.z = f2b((v.z-mu)*rs*gv.z + bv.z);
    o4.w = f2b((v.w-mu)*rs*gv.w + bv.w);
    ((ushort4*)(Qn + (size_t)bid*1024))[t] = o4;
  } else if(bid < 4096){                // ---- gather K/V ----
    int row = bid - 2048;               // 0..2047
    int isV = row>>10, r = row&1023;
    int b = r>>9, jj = r&511;
    const float* src = (isV? V : K) + ((size_t)(b*1024 + vf[jj]))*1024;
    unsigned short* dst = (isV? Vg : Kg) + (size_t)r*1024;
    float4 v = ((const float4*)src)[t];
    ushort4 o; o.x=f2b(v.x); o.y=f2b(v.y); o.z=f2b(v.z); o.w=f2b(v.w);
    ((ushort4*)dst)[t] = o;
  } else if(bid < 4608){                // ---- cast lookup table ----
    int i = (bid-4096)*256 + t;
    if(i < 2047*64) Lb[i] = f2b(L[i]);
  } else if(bid < 5632){                // ---- weight transpose ----
    int idx = bid - 4608;               // 0..1023
    int z = idx>>8, rem = idx&255;
    int k0 = (rem&15)*64, n0 = (rem>>4)*64;
    const float* S = z==0?W0: z==1?W1: z==2?W2:W3;
    unsigned short* D = z==0?D0: z==1?D1: z==2?D2:D3;
    int tr = t>>6, tc = t&63;
    #pragma unroll
    for(int it=0;it<16;it++){ int r = it*4+tr; tile[r][tc] = S[(size_t)(k0+r)*1024 + n0+tc]; }
    __syncthreads();
    #pragma unroll
    for(int it=0;it<16;it++){ int r = it*4+tr; D[(size_t)(n0+r)*1024 + k0+tc] = f2b(tile[tc][r]); }
  } else {                              // ---- mask pre-pack ----
    const int mb = bid - 5632;          // 0..2047
    const size_t g0 = (size_t)mb*16;    // 16 global rows
    if(t==0){ cnt1=0; cnt23=0; }
    __syncthreads();
    const uint4* bp = (const uint4*)(mkb + g0*512);
    int l1=0,l23=0;
    #pragma unroll
    for(int i=0;i<2;i++){
      uint4 v = bp[t + i*256];
      unsigned int ws[4] = {v.x,v.y,v.z,v.w};
      #pragma unroll
      for(int j=0;j<4;j++){
        if((ws[j]>>8)&0xFFu) l1++;
        if(ws[j]>>16)        l23++;
      }
    }
    #pragma unroll
    for(int o=1;o<64;o<<=1){ l1 += __shfl_xor(l1,o); l23 += __shfl_xor(l23,o); }
    if((t&63)==0){ atomicAdd(&cnt1,l1); atomicAdd(&cnt23,l23); }
    __syncthreads();
    const int flag = cnt1 ? 1 : (cnt23 ? 2 : 0);
    const int rl = t>>4, f = t&15;
    const size_t base = (g0 + rl)*512 + f;
    unsigned int word = 0;
    if(flag==0){
      const int* p = (const int*)mkb;
      #pragma unroll
      for(int i=0;i<32;i++) word |= (p[base+i*16]!=0 ? 1u:0u) << i;
    } else if(flag==1){
      #pragma unroll
      for(int i=0;i<32;i++) word |= (mkb[base+i*16]!=0 ? 1u:0u) << i;
    } else {
      const float* p = (const float*)mkb;
      #pragma unroll
      for(int i=0;i<32;i++) word |= (p[base+i*16]!=0.f ? 1u:0u) << i;
    }
    MB[((size_t)mb*4 + (t>>6))*64 + f*4 + (rl&3)] = word;
  }
}

// ---------- projection GEMM, 64x128 tile, 512 blocks (reg-staging) ----------
__global__ __launch_bounds__(256) void k_proj(
    const short* __restrict__ QN, const short* __restrict__ WQT,
    const short* __restrict__ KG, const short* __restrict__ WKT,
    const short* __restrict__ WVT, const short* __restrict__ VG,
    unsigned short* __restrict__ QB, unsigned short* __restrict__ KB,
    unsigned short* __restrict__ VT){
  __shared__ __align__(16) short Ab[64*32];
  __shared__ __align__(16) short Bb[128*32];
  int bid = blockIdx.x;
  int mode, bx;
  if(bid<256){ mode=0; bx=bid>>3; }
  else if(bid<384){ mode=1; bx=(bid-256)>>3; }
  else { mode=2; bx=(bid-384)>>3; }
  int by = bid&7;
  const short* A  = mode==0? QN : mode==1? KG : WVT;
  const short* Bt = mode==0? WQT: mode==1? WKT: VG;

  const int t = threadIdx.x;
  const int w = t>>6, l = t&63;
  const int fl15 = l&15, fl4 = l>>4;
  const size_t m0 = (size_t)bx*64, n0 = (size_t)by*128;
  const int srow = t>>2, scb = t&3;
  const int sg = scb ^ ((srow>>1)&3);
  const short* Ap = A + (m0+srow)*1024 + 8*sg;
  const short* Bp = Bt + (n0+srow)*1024 + 8*sg;

  f32x4 acc[4][2];
  const f32x4 zero = {0.f,0.f,0.f,0.f};
  #pragma unroll
  for(int m=0;m<4;m++)
    #pragma unroll
    for(int n=0;n<2;n++) acc[m][n] = zero;

  for(int k0=0;k0<1024;k0+=32){
    s16x8 a0 = *(const s16x8*)(Ap + k0);
    s16x8 b0 = *(const s16x8*)(Bp + k0);
    s16x8 b1 = *(const s16x8*)(Bp + 64*1024 + k0);
    __syncthreads();
    *(s16x8*)(Ab + srow*32 + scb*8)      = a0;
    *(s16x8*)(Bb + srow*32 + scb*8)      = b0;
    *(s16x8*)(Bb + (64+srow)*32 + scb*8) = b1;
    __syncthreads();
    s16x8 af[4], bff[2];
    #pragma unroll
    for(int m=0;m<4;m++){
      int row = m*16 + fl15;
      int gg = fl4 ^ ((row>>1)&3);
      af[m] = *(const s16x8*)(Ab + row*32 + gg*8);
    }
    #pragma unroll
    for(int n=0;n<2;n++){
      int row = w*32 + n*16 + fl15;
      int gg = fl4 ^ ((row>>1)&3);
      bff[n] = *(const s16x8*)(Bb + row*32 + gg*8);
    }
    #pragma unroll
    for(int m=0;m<4;m++)
      #pragma unroll
      for(int n=0;n<2;n++)
        acc[m][n] = MFMA(af[m], bff[n], acc[m][n]);
  }

  #pragma unroll
  for(int m=0;m<4;m++){
    #pragma unroll
    for(int n=0;n<2;n++){
      int mgb = (int)m0 + m*16 + 4*fl4;
      int ng  = (int)n0 + w*32 + n*16 + fl15;
      #pragma unroll
      for(int p=0;p<4;p++){
        int mg = mgb + p;
        float v = acc[m][n][p];
        if(mode==0){ int b=mg>>10, i=mg&1023, h=ng>>6, d=ng&63;
          QB[((size_t)((b*16+h)*1024+i))*64 + d] = f2b(v); }
        else if(mode==1){ int b=mg>>9, jj=mg&511, h=ng>>6, d=ng&63;
          KB[((size_t)((b*16+h)*512+jj))*64 + d] = f2b(v); }
        else { int h=mg>>6, d=mg&63, b=ng>>9, jj=ng&511;
          VT[((size_t)((b*16+h)*64+d))*512 + jj] = f2b(v); }
      }
    }
  }
}

// ---------- output GEMM, 64x128 tile, 256 blocks (reg-staging) ----------
__global__ __launch_bounds__(256) void k_gemmO(
    const short* __restrict__ A, const short* __restrict__ Bt,
    float* __restrict__ out, const float* __restrict__ bo,
    const float* __restrict__ ctxf){
  __shared__ __align__(16) short Ab[64*32];
  __shared__ __align__(16) short Bb[128*32];
  const int bid = blockIdx.x;
  const int bx = bid>>3, by = bid&7;
  const int t = threadIdx.x;
  const int w = t>>6, l = t&63;
  const int fl15 = l&15, fl4 = l>>4;
  const size_t m0 = (size_t)bx*64, n0 = (size_t)by*128;
  const int srow = t>>2, scb = t&3;
  const int sg = scb ^ ((srow>>1)&3);
  const short* Ap = A + (m0+srow)*1024 + 8*sg;
  const short* Bp = Bt + (n0+srow)*1024 + 8*sg;

  f32x4 acc[4][2];
  const f32x4 zero = {0.f,0.f,0.f,0.f};
  #pragma unroll
  for(int m=0;m<4;m++)
    #pragma unroll
    for(int n=0;n<2;n++) acc[m][n] = zero;

  for(int k0=0;k0<1024;k0+=32){
    s16x8 a0 = *(const s16x8*)(Ap + k0);
    s16x8 b0 = *(const s16x8*)(Bp + k0);
    s16x8 b1 = *(const s16x8*)(Bp + 64*1024 + k0);
    __syncthreads();
    *(s16x8*)(Ab + srow*32 + scb*8)      = a0;
    *(s16x8*)(Bb + srow*32 + scb*8)      = b0;
    *(s16x8*)(Bb + (64+srow)*32 + scb*8) = b1;
    __syncthreads();
    s16x8 af[4], bff[2];
    #pragma unroll
    for(int m=0;m<4;m++){
      int row = m*16 + fl15;
      int gg = fl4 ^ ((row>>1)&3);
      af[m] = *(const s16x8*)(Ab + row*32 + gg*8);
    }
    #pragma unroll
    for(int n=0;n<2;n++){
      int row = w*32 + n*16 + fl15;
      int gg = fl4 ^ ((row>>1)&3);
      bff[n] = *(const s16x8*)(Bb + row*32 + gg*8);
    }
    #pragma unroll
    for(int m=0;m<4;m++)
      #pragma unroll
      for(int n=0;n<2;n++)
        acc[m][n] = MFMA(af[m], bff[n], acc[m][n]);
  }

  #pragma unroll
  for(int m=0;m<4;m++){
    #pragma unroll
    for(int n=0;n<2;n++){
      int mgb = (int)m0 + m*16 + 4*fl4;
      int ng  = (int)n0 + w*32 + n*16 + fl15;
      #pragma unroll
      for(int p=0;p<4;p++){
        int mg = mgb + p;
        size_t idx = (size_t)mg*1024 + ng;
        out[idx] = acc[m][n][p] + bo[ng] + ctxf[idx];
      }
    }
  }
}

// ---------- fused rel + flash attention: 4 blocks/CU (RGS=18), 4 barriers ----------
// vs r16/r18: G padding 20->18 shorts (LDS 43,520 -> 39,168 B <= 40,960) so 4
// blocks/CU fit; __launch_bounds__(512,8). Phase-1 write = two 4B u32 stores
// (36B row stride breaks b64 align at odd u). Gather: elem (X-r,r) at
// X*18 - 68*fl4 - 17*p. Merge MG stride 18 f32, float2-pair accesses (8B align).
#define G_RGS 18
#define G_ROWS 272
__global__ __launch_bounds__(512,8) void k_attn(const short* __restrict__ qb,
    const short* __restrict__ kb, const short* __restrict__ vt,
    const short* __restrict__ lbf, const int* __restrict__ vf,
    const unsigned int* __restrict__ MB,
    unsigned short* __restrict__ ctxb, float* __restrict__ ctxf){
  __shared__ __align__(16) short Gs[4][G_ROWS*G_RGS];   // 39,168 B (aliased: P buf, merge buf)
  const int t=threadIdx.x, w=t>>6, l=t&63, fl15=l&15, fl4=l>>4;
  const int logical = ((blockIdx.x & 7) << 8) + (blockIdx.x >> 3);
  const int bh = logical >> 6;    // 0..31
  const int qg = logical & 63;    // 0..63
  const int qw = qg*16;

  // ===== early independent global loads =====
  const short* qp = qb + ((size_t)(bh*1024 + qw + fl15))*64 + 8*fl4;
  s16x8 qa0 = *(const s16x8*)qp;
  s16x8 qa1 = *(const s16x8*)(qp+32);
  const int rowgrp = bh*256 + qg*4 + fl4;
  uint4 mv = ((const uint4*)MB)[rowgrp*16 + fl15];

  const short* kp_row = kb + ((size_t)(bh*512 + fl15))*64 + 8*fl4;
  s16x8 kf[8];
  #pragma unroll
  for(int i=0;i<4;i++){
    const short* ka = kp_row + (size_t)(4*w+i)*1024;
    kf[2*i]   = *(const s16x8*)ka;
    kf[2*i+1] = *(const s16x8*)(ka+32);
  }
  const int vf0 = vf[0];
  int ov[4];
  #pragma unroll
  for(int i=0;i<4;i++) ov[i] = vf[(4*w+i)*16 + fl15] - vf0;   // 0..1023

  const int x0  = 1008 + vf0 - qw;            // >= 0
  const int cw  = w&3;
  const int xcw = x0 + cw*256;

  // ---- phase 1: G chunk cw, unskewed, tile range split between wave pair ----
  short* Gw = &Gs[cw][0];
  const f32x4 zero = {0.f,0.f,0.f,0.f};
  const int tbeg = (w>>2)? 9 : 0;
  const int tend = (w>>2)? 17 : 9;
  for(int tt=tbeg; tt<tend; tt++){
    int xr = xcw + tt*16 + fl15; if(xr>2046) xr = 2046;
    const short* lp = lbf + (size_t)xr*64 + 8*fl4;
    s16x8 b0 = *(const s16x8*)lp;
    s16x8 b1 = *(const s16x8*)(lp+32);
    f32x4 a = zero;
    a = MFMA(qa0,b0,a); a = MFMA(qa1,b1,a);
    unsigned int pk0 = (unsigned int)f2b(a[0]) | ((unsigned int)f2b(a[1])<<16);
    unsigned int pk1 = (unsigned int)f2b(a[2]) | ((unsigned int)f2b(a[3])<<16);
    int u = tt*16 + fl15;
    int uoff = u*G_RGS + 4*fl4;                 // shorts; 4B-aligned
    *(unsigned int*)(Gw + uoff)     = pk0;      // rows 4*fl4,4*fl4+1 at col u
    *(unsigned int*)(Gw + uoff + 2) = pk1;      // rows 4*fl4+2,4*fl4+3
  }

  unsigned int mbits[4] = {mv.x, mv.y, mv.z, mv.w};
  __syncthreads();   // (1) G ready for cross-wave reads

  // ---- phase 2: rel gathers (scalar b16), then register flash on 64 keys ----
  short rlv[4][4];
  #pragma unroll
  for(int i=0;i<4;i++){
    int o = ov[i];
    const short* gc = &Gs[o>>8][((o&255)+15)*G_RGS - 68*fl4];
    #pragma unroll
    for(int p=0;p<4;p++) rlv[i][p] = gc[-17*p];      // Gs[c][(o&255)+15-r][r], r=4*fl4+p
  }
  __syncthreads();   // (2) Gs now reusable as P buffer

  // QK^T + rel + mask
  f32x4 S[4];
  #pragma unroll
  for(int tl=0;tl<4;tl++){
    int ttg = 4*w + tl;
    f32x4 a = zero;
    a = MFMA(qa0, kf[2*tl], a); a = MFMA(qa1, kf[2*tl+1], a);
    #pragma unroll
    for(int p=0;p<4;p++){
      float sv = (a[p] + b2f((unsigned short)rlv[tl][p])) * 0.125f;
      bool mskb = (mbits[p]>>ttg)&1u;
      a[p] = mskb ? -1e30f : sv;
    }
    S[tl] = a;
  }

  // V fragments (issued here so K regs die first)
  const short* vpb[4];
  #pragma unroll
  for(int dt=0;dt<4;dt++)
    vpb[dt] = vt + ((size_t)(bh*64 + dt*16 + fl15))*512 + w*64 + 8*fl4;
  s16x8 vfr[8];
  #pragma unroll
  for(int dt=0;dt<4;dt++){
    vfr[2*dt]   = *(const s16x8*)(vpb[dt]);
    vfr[2*dt+1] = *(const s16x8*)(vpb[dt] + 32);
  }

  // row max, exp, sum, P -> LDS
  float m_run[4], ps[4];
  #pragma unroll
  for(int p=0;p<4;p++){
    float cm = fmaxf(fmaxf(S[0][p],S[1][p]), fmaxf(S[2][p],S[3][p]));
    #pragma unroll
    for(int o=1;o<16;o<<=1) cm = fmaxf(cm, __shfl_xor(cm,o));
    m_run[p] = cm;
    ps[p] = 0.f;
  }
  short* Pw = ((short*)Gs) + w*1024;             // 8 waves x 2 KiB = 16 KiB
  #pragma unroll
  for(int tl=0;tl<4;tl++){
    int col = (tl*16 + fl15) ^ (fl4<<4);
    #pragma unroll
    for(int p=0;p<4;p++){
      float e = __expf(S[tl][p]-m_run[p]);
      ps[p] += e;
      Pw[(4*fl4+p)*64 + col] = (short)f2b(e);
    }
  }
  // PV accumulate
  f32x4 facc[4];
  #pragma unroll
  for(int dt=0;dt<4;dt++) facc[dt] = zero;
  #pragma unroll
  for(int s=0;s<2;s++){
    s16x8 pa = *(const s16x8*)(Pw + fl15*64 + ((s*32 + fl4*8) ^ ((fl15>>2)<<4)));
    #pragma unroll
    for(int dt=0;dt<4;dt++)
      facc[dt] = MFMA(pa, vfr[2*dt+s], facc[dt]);
  }

  // reduce ps across the 16 fl15 lanes
  #pragma unroll
  for(int p=0;p<4;p++){
    #pragma unroll
    for(int o=1;o<16;o<<=1) ps[p] += __shfl_xor(ps[p],o);
  }

  // ---- phase 3: 8-way split-K merge, RAW write + single barrier ----
  __syncthreads();   // (3) all P reads (PV) done; Gs reusable as merge buffer
  float* MT = (float*)&Gs[0][0];                        // [8][16]  bytes 0..511
  float* ST = MT + 128;                                 // [8][16]  bytes 512..1023
  float* MG = (float*)(((char*)&Gs[0][0]) + 1024);      // [8][4][16][18] f32 = 36,864 B
  if(fl15==0){
    #pragma unroll
    for(int p=0;p<4;p++){ MT[w*16 + 4*fl4+p] = m_run[p]; ST[w*16 + 4*fl4+p] = ps[p]; }
  }
  #pragma unroll
  for(int dt=0;dt<4;dt++){
    int idx = ((w*4+dt)*16 + fl15)*G_RGS + 4*fl4;       // x4B: 72*row+16*fl4 -> 8B-aligned
    float2 lo = {facc[dt][0], facc[dt][1]};
    float2 hi = {facc[dt][2], facc[dt][3]};
    *(float2*)&MG[idx]     = lo;
    *(float2*)&MG[idx + 2] = hi;
  }
  __syncthreads();   // (4)
  // waves 0..3: compute all 8 scales per row, weighted-sum, store d-slice dt=w
  if(w < 4){
    float den[4], ek[8][4];
    #pragma unroll
    for(int p=0;p<4;p++){
      int row = 4*fl4+p;
      float m = -1e30f;
      #pragma unroll
      for(int k=0;k<8;k++) m = fmaxf(m, MT[k*16+row]);
      float d = 0.f;
      #pragma unroll
      for(int k=0;k<8;k++){
        float e = __expf(MT[k*16+row]-m);
        ek[k][p] = e;
        d += e*ST[k*16+row];
      }
      den[p] = d;
    }
    f32x4 vs = zero;
    #pragma unroll
    for(int k=0;k<8;k++){
      int idx = ((k*4+w)*16 + fl15)*G_RGS + 4*fl4;
      float2 lo = *(const float2*)&MG[idx];
      float2 hi = *(const float2*)&MG[idx + 2];
      vs[0] += ek[k][0]*lo.x; vs[1] += ek[k][1]*lo.y;
      vs[2] += ek[k][2]*hi.x; vs[3] += ek[k][3]*hi.y;
    }
    const int b = bh>>4, h = bh&15;
    #pragma unroll
    for(int p=0;p<4;p++){
      float v = vs[p] / den[p];
      int row = 4*fl4+p;
      size_t idx = ((size_t)(b*1024 + qw + row))*1024 + h*64 + w*16 + fl15;
      ctxb[idx] = f2b(v);
      ctxf[idx] = v;
    }
  }
}

// ---------- launch ----------
extern "C" void kernel_launch(void* const* d_in, const int* in_sizes, int n_in,
                              void* d_out, int out_size, void* d_ws, size_t ws_size,
                              hipStream_t stream){
  (void)in_sizes; (void)n_in; (void)out_size; (void)ws_size;
  const float* Q  = (const float*)d_in[0];
  const float* K  = (const float*)d_in[1];
  const float* V  = (const float*)d_in[2];
  const float* Lt = (const float*)d_in[3];
  const int*   vf = (const int*)d_in[4];
  const void*  mk = d_in[5];
  const float* Wq = (const float*)d_in[6];
  const float* Wk = (const float*)d_in[7];
  const float* Wv = (const float*)d_in[8];
  const float* Wo = (const float*)d_in[9];
  const float* bo = (const float*)d_in[10];
  const float* lg = (const float*)d_in[11];
  const float* lb = (const float*)d_in[12];

  char* base = (char*)d_ws;
  size_t off = 0;
  auto alloc = [&](size_t bytes)->char*{
    char* p = base + off; off += (bytes + 255) & ~(size_t)255; return p; };
  unsigned int*   MBp = (unsigned int*)alloc(32768ull*16*4);
  unsigned short* QN  = (unsigned short*)alloc(2048ull*1024*2);
  unsigned short* KG  = (unsigned short*)alloc(1024ull*1024*2);
  unsigned short* VG  = (unsigned short*)alloc(1024ull*1024*2);
  unsigned short* WQT = (unsigned short*)alloc(1024ull*1024*2);
  unsigned short* WKT = (unsigned short*)alloc(1024ull*1024*2);
  unsigned short* WVT = (unsigned short*)alloc(1024ull*1024*2);
  unsigned short* WOT = (unsigned short*)alloc(1024ull*1024*2);
  unsigned short* LB  = (unsigned short*)alloc(2047ull*64*2);
  unsigned short* QB  = (unsigned short*)alloc(32ull*1024*64*2);
  unsigned short* KB  = (unsigned short*)alloc(32ull*512*64*2);
  unsigned short* VT  = (unsigned short*)alloc(32ull*64*512*2);
  unsigned short* CB  = (unsigned short*)alloc(2048ull*1024*2);
  float*          CF  = (float*)alloc(2048ull*1024*4);

  k_prep<<<7680,256,0,stream>>>(Q, lg, lb, QN, K, V, vf, KG, VG, Lt, LB,
                                Wq, Wk, Wv, Wo, WQT, WKT, WVT, WOT,
                                (const unsigned char*)mk, MBp);
  k_proj<<<512,256,0,stream>>>((const short*)QN,(const short*)WQT,
                               (const short*)KG,(const short*)WKT,
                               (const short*)WVT,(const short*)VG,
                               QB, KB, VT);
  k_attn<<<2048,512,0,stream>>>((const short*)QB,(const short*)KB,(const short*)VT,
                                (const short*)LB, vf, MBp, CB, CF);
  k_gemmO<<<256,256,0,stream>>>((const short*)CB,(const short*)WOT,
                                (float*)d_out, bo, CF);
}

// Round 20
// 133.265 us; speedup vs baseline: 1.0357x; 1.0357x over previous
//
#include <hip/hip_runtime.h>
#include <stdint.h>
#include <stddef.h>

// ---------- types ----------
typedef __attribute__((ext_vector_type(8))) short s16x8;
typedef __attribute__((ext_vector_type(4))) short s16x4;
typedef __attribute__((ext_vector_type(4))) float f32x4;
typedef __attribute__((ext_vector_type(2))) unsigned int u32x2;

#define MFMA(a,b,c) __builtin_amdgcn_mfma_f32_16x16x32_bf16((a),(b),(c),0,0,0)

static __device__ __forceinline__ unsigned short f2b(float f){
  unsigned int b = __float_as_uint(f);
  b = (b + 0x7FFFu + ((b>>16)&1u)) >> 16;     // RNE
  return (unsigned short)b;
}
static __device__ __forceinline__ float b2f(unsigned short u){
  return __uint_as_float(((unsigned int)u)<<16);
}

// B=2, T1=1024, T2=512, H=16, DH=64, DM=1024, SCALE=0.125

// ---------- fused prep: LN(Q), gather K/V, cast L, transpose weights, mask pack ----------
__global__ __launch_bounds__(256) void k_prep(
    const float* __restrict__ Q, const float* __restrict__ g, const float* __restrict__ be,
    unsigned short* __restrict__ Qn,
    const float* __restrict__ K, const float* __restrict__ V, const int* __restrict__ vf,
    unsigned short* __restrict__ Kg, unsigned short* __restrict__ Vg,
    const float* __restrict__ L, unsigned short* __restrict__ Lb,
    const float* __restrict__ W0, const float* __restrict__ W1,
    const float* __restrict__ W2, const float* __restrict__ W3,
    unsigned short* __restrict__ D0, unsigned short* __restrict__ D1,
    unsigned short* __restrict__ D2, unsigned short* __restrict__ D3,
    const unsigned char* __restrict__ mkb, unsigned int* __restrict__ MB){
  __shared__ float tile[64][65];
  __shared__ float red[8];
  __shared__ int cnt1, cnt23;
  const int bid = blockIdx.x, t = threadIdx.x;
  if(bid < 2048){                       // ---- LayerNorm ----
    const float4* xp = (const float4*)(Q + (size_t)bid*1024);
    float4 v = xp[t];
    float s  = v.x+v.y+v.z+v.w;
    float s2 = v.x*v.x+v.y*v.y+v.z*v.z+v.w*v.w;
    #pragma unroll
    for(int o=1;o<64;o<<=1){ s += __shfl_xor(s,o); s2 += __shfl_xor(s2,o); }
    int w = t>>6, l = t&63;
    if(l==0){ red[w]=s; red[4+w]=s2; }
    __syncthreads();
    s  = red[0]+red[1]+red[2]+red[3];
    s2 = red[4]+red[5]+red[6]+red[7];
    float mu = s*(1.f/1024.f);
    float var = s2*(1.f/1024.f) - mu*mu;
    float rs = rsqrtf(var + 1e-5f);
    float4 gv = ((const float4*)g)[t];
    float4 bv = ((const float4*)be)[t];
    ushort4 o4;
    o4.x = f2b((v.x-mu)*rs*gv.x + bv.x);
    o4.y = f2b((v.y-mu)*rs*gv.y + bv.y);
    o4.z = f2b((v.z-mu)*rs*gv.z + bv.z);
    o4.w = f2b((v.w-mu)*rs*gv.w + bv.w);
    ((ushort4*)(Qn + (size_t)bid*1024))[t] = o4;
  } else if(bid < 4096){                // ---- gather K/V ----
    int row = bid - 2048;               // 0..2047
    int isV = row>>10, r = row&1023;
    int b = r>>9, jj = r&511;
    const float* src = (isV? V : K) + ((size_t)(b*1024 + vf[jj]))*1024;
    unsigned short* dst = (isV? Vg : Kg) + (size_t)r*1024;
    float4 v = ((const float4*)src)[t];
    ushort4 o; o.x=f2b(v.x); o.y=f2b(v.y); o.z=f2b(v.z); o.w=f2b(v.w);
    ((ushort4*)dst)[t] = o;
  } else if(bid < 4608){                // ---- cast lookup table ----
    int i = (bid-4096)*256 + t;
    if(i < 2047*64) Lb[i] = f2b(L[i]);
  } else if(bid < 5632){                // ---- weight transpose ----
    int idx = bid - 4608;               // 0..1023
    int z = idx>>8, rem = idx&255;
    int k0 = (rem&15)*64, n0 = (rem>>4)*64;
    const float* S = z==0?W0: z==1?W1: z==2?W2:W3;
    unsigned short* D = z==0?D0: z==1?D1: z==2?D2:D3;
    int tr = t>>6, tc = t&63;
    #pragma unroll
    for(int it=0;it<16;it++){ int r = it*4+tr; tile[r][tc] = S[(size_t)(k0+r)*1024 + n0+tc]; }
    __syncthreads();
    #pragma unroll
    for(int it=0;it<16;it++){ int r = it*4+tr; D[(size_t)(n0+r)*1024 + k0+tc] = f2b(tile[tc][r]); }
  } else {                              // ---- mask pre-pack ----
    const int mb = bid - 5632;          // 0..2047
    const size_t g0 = (size_t)mb*16;    // 16 global rows
    if(t==0){ cnt1=0; cnt23=0; }
    __syncthreads();
    const uint4* bp = (const uint4*)(mkb + g0*512);
    int l1=0,l23=0;
    #pragma unroll
    for(int i=0;i<2;i++){
      uint4 v = bp[t + i*256];
      unsigned int ws[4] = {v.x,v.y,v.z,v.w};
      #pragma unroll
      for(int j=0;j<4;j++){
        if((ws[j]>>8)&0xFFu) l1++;
        if(ws[j]>>16)        l23++;
      }
    }
    #pragma unroll
    for(int o=1;o<64;o<<=1){ l1 += __shfl_xor(l1,o); l23 += __shfl_xor(l23,o); }
    if((t&63)==0){ atomicAdd(&cnt1,l1); atomicAdd(&cnt23,l23); }
    __syncthreads();
    const int flag = cnt1 ? 1 : (cnt23 ? 2 : 0);
    const int rl = t>>4, f = t&15;
    const size_t base = (g0 + rl)*512 + f;
    unsigned int word = 0;
    if(flag==0){
      const int* p = (const int*)mkb;
      #pragma unroll
      for(int i=0;i<32;i++) word |= (p[base+i*16]!=0 ? 1u:0u) << i;
    } else if(flag==1){
      #pragma unroll
      for(int i=0;i<32;i++) word |= (mkb[base+i*16]!=0 ? 1u:0u) << i;
    } else {
      const float* p = (const float*)mkb;
      #pragma unroll
      for(int i=0;i<32;i++) word |= (p[base+i*16]!=0.f ? 1u:0u) << i;
    }
    MB[((size_t)mb*4 + (t>>6))*64 + f*4 + (rl&3)] = word;
  }
}

// ---------- projection GEMM, 64x128 tile, 512 blocks (reg-staging) ----------
__global__ __launch_bounds__(256) void k_proj(
    const short* __restrict__ QN, const short* __restrict__ WQT,
    const short* __restrict__ KG, const short* __restrict__ WKT,
    const short* __restrict__ WVT, const short* __restrict__ VG,
    unsigned short* __restrict__ QB, unsigned short* __restrict__ KB,
    unsigned short* __restrict__ VT){
  __shared__ __align__(16) short Ab[64*32];
  __shared__ __align__(16) short Bb[128*32];
  int bid = blockIdx.x;
  int mode, bx;
  if(bid<256){ mode=0; bx=bid>>3; }
  else if(bid<384){ mode=1; bx=(bid-256)>>3; }
  else { mode=2; bx=(bid-384)>>3; }
  int by = bid&7;
  const short* A  = mode==0? QN : mode==1? KG : WVT;
  const short* Bt = mode==0? WQT: mode==1? WKT: VG;

  const int t = threadIdx.x;
  const int w = t>>6, l = t&63;
  const int fl15 = l&15, fl4 = l>>4;
  const size_t m0 = (size_t)bx*64, n0 = (size_t)by*128;
  const int srow = t>>2, scb = t&3;
  const int sg = scb ^ ((srow>>1)&3);
  const short* Ap = A + (m0+srow)*1024 + 8*sg;
  const short* Bp = Bt + (n0+srow)*1024 + 8*sg;

  f32x4 acc[4][2];
  const f32x4 zero = {0.f,0.f,0.f,0.f};
  #pragma unroll
  for(int m=0;m<4;m++)
    #pragma unroll
    for(int n=0;n<2;n++) acc[m][n] = zero;

  for(int k0=0;k0<1024;k0+=32){
    s16x8 a0 = *(const s16x8*)(Ap + k0);
    s16x8 b0 = *(const s16x8*)(Bp + k0);
    s16x8 b1 = *(const s16x8*)(Bp + 64*1024 + k0);
    __syncthreads();
    *(s16x8*)(Ab + srow*32 + scb*8)      = a0;
    *(s16x8*)(Bb + srow*32 + scb*8)      = b0;
    *(s16x8*)(Bb + (64+srow)*32 + scb*8) = b1;
    __syncthreads();
    s16x8 af[4], bff[2];
    #pragma unroll
    for(int m=0;m<4;m++){
      int row = m*16 + fl15;
      int gg = fl4 ^ ((row>>1)&3);
      af[m] = *(const s16x8*)(Ab + row*32 + gg*8);
    }
    #pragma unroll
    for(int n=0;n<2;n++){
      int row = w*32 + n*16 + fl15;
      int gg = fl4 ^ ((row>>1)&3);
      bff[n] = *(const s16x8*)(Bb + row*32 + gg*8);
    }
    #pragma unroll
    for(int m=0;m<4;m++)
      #pragma unroll
      for(int n=0;n<2;n++)
        acc[m][n] = MFMA(af[m], bff[n], acc[m][n]);
  }

  #pragma unroll
  for(int m=0;m<4;m++){
    #pragma unroll
    for(int n=0;n<2;n++){
      int mgb = (int)m0 + m*16 + 4*fl4;
      int ng  = (int)n0 + w*32 + n*16 + fl15;
      #pragma unroll
      for(int p=0;p<4;p++){
        int mg = mgb + p;
        float v = acc[m][n][p];
        if(mode==0){ int b=mg>>10, i=mg&1023, h=ng>>6, d=ng&63;
          QB[((size_t)((b*16+h)*1024+i))*64 + d] = f2b(v); }
        else if(mode==1){ int b=mg>>9, jj=mg&511, h=ng>>6, d=ng&63;
          KB[((size_t)((b*16+h)*512+jj))*64 + d] = f2b(v); }
        else { int h=mg>>6, d=mg&63, b=ng>>9, jj=ng&511;
          VT[((size_t)((b*16+h)*64+d))*512 + jj] = f2b(v); }
      }
    }
  }
}

// ---------- output GEMM, 64x128 tile, 256 blocks (reg-staging) ----------
__global__ __launch_bounds__(256) void k_gemmO(
    const short* __restrict__ A, const short* __restrict__ Bt,
    float* __restrict__ out, const float* __restrict__ bo,
    const float* __restrict__ ctxf){
  __shared__ __align__(16) short Ab[64*32];
  __shared__ __align__(16) short Bb[128*32];
  const int bid = blockIdx.x;
  const int bx = bid>>3, by = bid&7;
  const int t = threadIdx.x;
  const int w = t>>6, l = t&63;
  const int fl15 = l&15, fl4 = l>>4;
  const size_t m0 = (size_t)bx*64, n0 = (size_t)by*128;
  const int srow = t>>2, scb = t&3;
  const int sg = scb ^ ((srow>>1)&3);
  const short* Ap = A + (m0+srow)*1024 + 8*sg;
  const short* Bp = Bt + (n0+srow)*1024 + 8*sg;

  f32x4 acc[4][2];
  const f32x4 zero = {0.f,0.f,0.f,0.f};
  #pragma unroll
  for(int m=0;m<4;m++)
    #pragma unroll
    for(int n=0;n<2;n++) acc[m][n] = zero;

  for(int k0=0;k0<1024;k0+=32){
    s16x8 a0 = *(const s16x8*)(Ap + k0);
    s16x8 b0 = *(const s16x8*)(Bp + k0);
    s16x8 b1 = *(const s16x8*)(Bp + 64*1024 + k0);
    __syncthreads();
    *(s16x8*)(Ab + srow*32 + scb*8)      = a0;
    *(s16x8*)(Bb + srow*32 + scb*8)      = b0;
    *(s16x8*)(Bb + (64+srow)*32 + scb*8) = b1;
    __syncthreads();
    s16x8 af[4], bff[2];
    #pragma unroll
    for(int m=0;m<4;m++){
      int row = m*16 + fl15;
      int gg = fl4 ^ ((row>>1)&3);
      af[m] = *(const s16x8*)(Ab + row*32 + gg*8);
    }
    #pragma unroll
    for(int n=0;n<2;n++){
      int row = w*32 + n*16 + fl15;
      int gg = fl4 ^ ((row>>1)&3);
      bff[n] = *(const s16x8*)(Bb + row*32 + gg*8);
    }
    #pragma unroll
    for(int m=0;m<4;m++)
      #pragma unroll
      for(int n=0;n<2;n++)
        acc[m][n] = MFMA(af[m], bff[n], acc[m][n]);
  }

  #pragma unroll
  for(int m=0;m<4;m++){
    #pragma unroll
    for(int n=0;n<2;n++){
      int mgb = (int)m0 + m*16 + 4*fl4;
      int ng  = (int)n0 + w*32 + n*16 + fl15;
      #pragma unroll
      for(int p=0;p<4;p++){
        int mg = mgb + p;
        size_t idx = (size_t)mg*1024 + ng;
        out[idx] = acc[m][n][p] + bo[ng] + ctxf[idx];
      }
    }
  }
}

// ---------- fused rel + flash attention: 3 blocks/CU, 4 barriers (best: r16/r18) ----------
#define G_RGS 20
#define G_ROWS 272
__global__ __launch_bounds__(512,6) void k_attn(const short* __restrict__ qb,
    const short* __restrict__ kb, const short* __restrict__ vt,
    const short* __restrict__ lbf, const int* __restrict__ vf,
    const unsigned int* __restrict__ MB,
    unsigned short* __restrict__ ctxb, float* __restrict__ ctxf){
  __shared__ __align__(16) short Gs[4][G_ROWS*G_RGS];   // 43,520 B (aliased: P buf, merge buf)
  const int t=threadIdx.x, w=t>>6, l=t&63, fl15=l&15, fl4=l>>4;
  const int logical = ((blockIdx.x & 7) << 8) + (blockIdx.x >> 3);
  const int bh = logical >> 6;    // 0..31
  const int qg = logical & 63;    // 0..63
  const int qw = qg*16;

  // ===== early independent global loads =====
  const short* qp = qb + ((size_t)(bh*1024 + qw + fl15))*64 + 8*fl4;
  s16x8 qa0 = *(const s16x8*)qp;
  s16x8 qa1 = *(const s16x8*)(qp+32);
  const int rowgrp = bh*256 + qg*4 + fl4;
  uint4 mv = ((const uint4*)MB)[rowgrp*16 + fl15];

  const short* kp_row = kb + ((size_t)(bh*512 + fl15))*64 + 8*fl4;
  s16x8 kf[8];
  #pragma unroll
  for(int i=0;i<4;i++){
    const short* ka = kp_row + (size_t)(4*w+i)*1024;
    kf[2*i]   = *(const s16x8*)ka;
    kf[2*i+1] = *(const s16x8*)(ka+32);
  }
  const int vf0 = vf[0];
  int ov[4];
  #pragma unroll
  for(int i=0;i<4;i++) ov[i] = vf[(4*w+i)*16 + fl15] - vf0;   // 0..1023

  const int x0  = 1008 + vf0 - qw;            // >= 0
  const int cw  = w&3;
  const int xcw = x0 + cw*256;

  // ---- phase 1: G chunk cw, unskewed, tile range split between wave pair ----
  short* Gw = &Gs[cw][0];
  const f32x4 zero = {0.f,0.f,0.f,0.f};
  const int tbeg = (w>>2)? 9 : 0;
  const int tend = (w>>2)? 17 : 9;
  for(int tt=tbeg; tt<tend; tt++){
    int xr = xcw + tt*16 + fl15; if(xr>2046) xr = 2046;
    const short* lp = lbf + (size_t)xr*64 + 8*fl4;
    s16x8 b0 = *(const s16x8*)lp;
    s16x8 b1 = *(const s16x8*)(lp+32);
    f32x4 a = zero;
    a = MFMA(qa0,b0,a); a = MFMA(qa1,b1,a);
    u32x2 pk;
    pk.x = (unsigned int)f2b(a[0]) | ((unsigned int)f2b(a[1])<<16);
    pk.y = (unsigned int)f2b(a[2]) | ((unsigned int)f2b(a[3])<<16);
    int u = tt*16 + fl15;
    *(u32x2*)(Gw + u*G_RGS + 4*fl4) = pk;    // rows 4*fl4..+3 at col u, one b64
  }

  unsigned int mbits[4] = {mv.x, mv.y, mv.z, mv.w};
  __syncthreads();   // (1) G ready for cross-wave reads

  // ---- phase 2: rel gathers (scalar b16), then register flash on 64 keys ----
  short rlv[4][4];
  #pragma unroll
  for(int i=0;i<4;i++){
    int o = ov[i];
    const short* gc = &Gs[o>>8][((o&255)+15)*G_RGS - 76*fl4];
    #pragma unroll
    for(int p=0;p<4;p++) rlv[i][p] = gc[-19*p];      // Gs[c][(o&255)+15-r][r], r=4*fl4+p
  }
  __syncthreads();   // (2) Gs now reusable as P buffer

  // QK^T + rel + mask
  f32x4 S[4];
  #pragma unroll
  for(int tl=0;tl<4;tl++){
    int ttg = 4*w + tl;
    f32x4 a = zero;
    a = MFMA(qa0, kf[2*tl], a); a = MFMA(qa1, kf[2*tl+1], a);
    #pragma unroll
    for(int p=0;p<4;p++){
      float sv = (a[p] + b2f((unsigned short)rlv[tl][p])) * 0.125f;
      bool mskb = (mbits[p]>>ttg)&1u;
      a[p] = mskb ? -1e30f : sv;
    }
    S[tl] = a;
  }

  // V fragments (issued here so K regs die first)
  const short* vpb[4];
  #pragma unroll
  for(int dt=0;dt<4;dt++)
    vpb[dt] = vt + ((size_t)(bh*64 + dt*16 + fl15))*512 + w*64 + 8*fl4;
  s16x8 vfr[8];
  #pragma unroll
  for(int dt=0;dt<4;dt++){
    vfr[2*dt]   = *(const s16x8*)(vpb[dt]);
    vfr[2*dt+1] = *(const s16x8*)(vpb[dt] + 32);
  }

  // row max, exp, sum, P -> LDS
  float m_run[4], ps[4];
  #pragma unroll
  for(int p=0;p<4;p++){
    float cm = fmaxf(fmaxf(S[0][p],S[1][p]), fmaxf(S[2][p],S[3][p]));
    #pragma unroll
    for(int o=1;o<16;o<<=1) cm = fmaxf(cm, __shfl_xor(cm,o));
    m_run[p] = cm;
    ps[p] = 0.f;
  }
  short* Pw = ((short*)Gs) + w*1024;             // 8 waves x 2 KiB
  #pragma unroll
  for(int tl=0;tl<4;tl++){
    int col = (tl*16 + fl15) ^ (fl4<<4);
    #pragma unroll
    for(int p=0;p<4;p++){
      float e = __expf(S[tl][p]-m_run[p]);
      ps[p] += e;
      Pw[(4*fl4+p)*64 + col] = (short)f2b(e);
    }
  }
  // PV accumulate
  f32x4 facc[4];
  #pragma unroll
  for(int dt=0;dt<4;dt++) facc[dt] = zero;
  #pragma unroll
  for(int s=0;s<2;s++){
    s16x8 pa = *(const s16x8*)(Pw + fl15*64 + ((s*32 + fl4*8) ^ ((fl15>>2)<<4)));
    #pragma unroll
    for(int dt=0;dt<4;dt++)
      facc[dt] = MFMA(pa, vfr[2*dt+s], facc[dt]);
  }

  // reduce ps across the 16 fl15 lanes
  #pragma unroll
  for(int p=0;p<4;p++){
    #pragma unroll
    for(int o=1;o<16;o<<=1) ps[p] += __shfl_xor(ps[p],o);
  }

  // ---- phase 3: 8-way split-K merge, RAW write + single barrier ----
  __syncthreads();   // (3) all P reads (PV) done; Gs reusable as merge buffer
  float* MT = (float*)&Gs[0][0];                        // [8][16]  bytes 0..511
  float* ST = MT + 128;                                 // [8][16]  bytes 512..1023
  float* MG = (float*)(((char*)&Gs[0][0]) + 1024);      // [8][4][16][20] f32 = 40,960 B
  if(fl15==0){
    #pragma unroll
    for(int p=0;p<4;p++){ MT[w*16 + 4*fl4+p] = m_run[p]; ST[w*16 + 4*fl4+p] = ps[p]; }
  }
  #pragma unroll
  for(int dt=0;dt<4;dt++)
    *(f32x4*)&MG[((w*4+dt)*16 + fl15)*20 + 4*fl4] = facc[dt];   // RAW partials
  __syncthreads();   // (4)
  // waves 0..3: compute all 8 scales per row, weighted-sum, store d-slice dt=w
  if(w < 4){
    float den[4], ek[8][4];
    #pragma unroll
    for(int p=0;p<4;p++){
      int row = 4*fl4+p;
      float m = -1e30f;
      #pragma unroll
      for(int k=0;k<8;k++) m = fmaxf(m, MT[k*16+row]);
      float d = 0.f;
      #pragma unroll
      for(int k=0;k<8;k++){
        float e = __expf(MT[k*16+row]-m);
        ek[k][p] = e;
        d += e*ST[k*16+row];
      }
      den[p] = d;
    }
    f32x4 vs = zero;
    #pragma unroll
    for(int k=0;k<8;k++){
      f32x4 raw = *(const f32x4*)&MG[((k*4+w)*16 + fl15)*20 + 4*fl4];
      #pragma unroll
      for(int p=0;p<4;p++) vs[p] += ek[k][p]*raw[p];
    }
    const int b = bh>>4, h = bh&15;
    #pragma unroll
    for(int p=0;p<4;p++){
      float v = vs[p] / den[p];
      int row = 4*fl4+p;
      size_t idx = ((size_t)(b*1024 + qw + row))*1024 + h*64 + w*16 + fl15;
      ctxb[idx] = f2b(v);
      ctxf[idx] = v;
    }
  }
}

// ---------- launch ----------
extern "C" void kernel_launch(void* const* d_in, const int* in_sizes, int n_in,
                              void* d_out, int out_size, void* d_ws, size_t ws_size,
                              hipStream_t stream){
  (void)in_sizes; (void)n_in; (void)out_size; (void)ws_size;
  const float* Q  = (const float*)d_in[0];
  const float* K  = (const float*)d_in[1];
  const float* V  = (const float*)d_in[2];
  const float* Lt = (const float*)d_in[3];
  const int*   vf = (const int*)d_in[4];
  const void*  mk = d_in[5];
  const float* Wq = (const float*)d_in[6];
  const float* Wk = (const float*)d_in[7];
  const float* Wv = (const float*)d_in[8];
  const float* Wo = (const float*)d_in[9];
  const float* bo = (const float*)d_in[10];
  const float* lg = (const float*)d_in[11];
  const float* lb = (const float*)d_in[12];

  char* base = (char*)d_ws;
  size_t off = 0;
  auto alloc = [&](size_t bytes)->char*{
    char* p = base + off; off += (bytes + 255) & ~(size_t)255; return p; };
  unsigned int*   MBp = (unsigned int*)alloc(32768ull*16*4);
  unsigned short* QN  = (unsigned short*)alloc(2048ull*1024*2);
  unsigned short* KG  = (unsigned short*)alloc(1024ull*1024*2);
  unsigned short* VG  = (unsigned short*)alloc(1024ull*1024*2);
  unsigned short* WQT = (unsigned short*)alloc(1024ull*1024*2);
  unsigned short* WKT = (unsigned short*)alloc(1024ull*1024*2);
  unsigned short* WVT = (unsigned short*)alloc(1024ull*1024*2);
  unsigned short* WOT = (unsigned short*)alloc(1024ull*1024*2);
  unsigned short* LB  = (unsigned short*)alloc(2047ull*64*2);
  unsigned short* QB  = (unsigned short*)alloc(32ull*1024*64*2);
  unsigned short* KB  = (unsigned short*)alloc(32ull*512*64*2);
  unsigned short* VT  = (unsigned short*)alloc(32ull*64*512*2);
  unsigned short* CB  = (unsigned short*)alloc(2048ull*1024*2);
  float*          CF  = (float*)alloc(2048ull*1024*4);

  k_prep<<<7680,256,0,stream>>>(Q, lg, lb, QN, K, V, vf, KG, VG, Lt, LB,
                                Wq, Wk, Wv, Wo, WQT, WKT, WVT, WOT,
                                (const unsigned char*)mk, MBp);
  k_proj<<<512,256,0,stream>>>((const short*)QN,(const short*)WQT,
                               (const short*)KG,(const short*)WKT,
                               (const short*)WVT,(const short*)VG,
                               QB, KB, VT);
  k_attn<<<2048,512,0,stream>>>((const short*)QB,(const short*)KB,(const short*)VT,
                                (const short*)LB, vf, MBp, CB, CF);
  k_gemmO<<<256,256,0,stream>>>((const short*)CB,(const short*)WOT,
                                (float*)d_out, bo, CF);
}